// Round 7
// baseline (168.780 us; speedup 1.0000x reference)
//
#include <hip/hip_runtime.h>

typedef unsigned short u16;
typedef unsigned int u32;
using frag16 = __attribute__((ext_vector_type(8))) short;   // 8 x bf16 (4 VGPRs)
using facc   = __attribute__((ext_vector_type(4))) float;   // 4 x fp32 acc
using facc16 = __attribute__((ext_vector_type(16))) float;  // 16 x fp32 acc

#define DEV static __device__ __forceinline__

DEV u16 f2bf(float f) {
  union { float f; unsigned u; } v; v.f = f;
  unsigned r = v.u + 0x7fffu + ((v.u >> 16) & 1u);
  return (u16)(r >> 16);
}
DEV unsigned fbits(float f) {
  union { float f; unsigned u; } v; v.f = f;
  return v.u;
}
// pack two fp32 -> two bf16 (lo in low half), round-half-up
DEV unsigned pkbf(float lo, float hi) {
  return __builtin_amdgcn_perm(fbits(hi) + 0x8000u, fbits(lo) + 0x8000u, 0x07060302u);
}
// truncating pack (no rounding adds) -- bias cancels num/denom for P.
DEV unsigned pkbf_t(float lo, float hi) {
  return __builtin_amdgcn_perm(fbits(hi), fbits(lo), 0x07060302u);
}
// async global->LDS, 16B per lane. LDS dest = wave-uniform base + lane*16.
DEV void gld16(const u16* g, u16* l) {
  __builtin_amdgcn_global_load_lds(
      (__attribute__((address_space(1))) unsigned int*)(g),
      (__attribute__((address_space(3))) unsigned int*)(l), 16, 0, 0);
}

// ---------------- K1: x cvt (0..1023, 64B/thread) + wtrans + gate -------------
__global__ __launch_bounds__(256) void prep_gate_kernel(const float4* __restrict__ x,
    const float* __restrict__ Wq, const float* __restrict__ Wk,
    const float* __restrict__ Wv, const float* __restrict__ Wo,
    const float* __restrict__ ctx, const float* __restrict__ W1,
    const float* __restrict__ b1, const float* __restrict__ W2,
    const float* __restrict__ b2,
    u16* __restrict__ xb, u16* __restrict__ WqT, u16* __restrict__ WkT,
    u16* __restrict__ WvT, u16* __restrict__ WoT, u16* __restrict__ gctx) {
  int bid = blockIdx.x;
  if (bid < 1024) {
    // x -> bf16: 4 float4 (64B) per thread
    int id = bid * 256 + threadIdx.x;
    const float4* xp = x + (size_t)id * 4;
    u16* op = xb + (size_t)id * 16;
    #pragma unroll
    for (int j = 0; j < 4; ++j) {
      float4 v = xp[j];
      ushort4 o;
      o.x = f2bf(v.x); o.y = f2bf(v.y); o.z = f2bf(v.z); o.w = f2bf(v.w);
      *(ushort4*)(op + j * 4) = o;
    }
  } else if (bid < 1168) {
    // 64x64 tile transpose via LDS: coalesced read AND write
    int job = bid - 1024;  // 0..143
    const float* W; u16* WT; int K, tile;
    if (job < 64)      { W = Wq; WT = WqT; K = 512; tile = job; }
    else if (job < 72) { W = Wk; WT = WkT; K = 64;  tile = job - 64; }
    else if (job < 80) { W = Wv; WT = WvT; K = 64;  tile = job - 72; }
    else               { W = Wo; WT = WoT; K = 512; tile = job - 80; }
    int tilesK = K >> 6;
    int tr = tile % tilesK, tc = tile / tilesK;
    __shared__ float tl[64][65];
    int c = threadIdx.x & 63, r4 = threadIdx.x >> 6;
    #pragma unroll
    for (int it = 0; it < 16; ++it) {
      int kk = it * 4 + r4;
      tl[kk][c] = W[(size_t)(tr * 64 + kk) * 512 + tc * 64 + c];
    }
    __syncthreads();
    #pragma unroll
    for (int it = 0; it < 16; ++it) {
      int nn = it * 4 + r4;
      WT[(size_t)(tc * 64 + nn) * K + tr * 64 + c] = f2bf(tl[c][nn]);
    }
  } else {
    // gate: gctx = bf16(ctx * sigmoid(relu(ctx@W1+b1)@W2+b2))
    int wave = threadIdx.x >> 6, lane = threadIdx.x & 63;
    int hi = lane >> 5, hl = lane & 31;
    int row = (bid - 1168) * 4 + wave;          // 8192 rows
    __shared__ float sc[4][64];
    float cv = ctx[(size_t)row * 64 + lane];
    sc[wave][lane] = cv;
    __syncthreads();
    float hp = 0.f;
    #pragma unroll
    for (int i = 0; i < 32; ++i) {
      int ii = hi * 32 + i;
      hp += sc[wave][ii] * W1[ii * 32 + hl];
    }
    hp += __shfl_xor(hp, 32);                    // full dot for unit hl
    float hr = fmaxf(hp + b1[hl], 0.f) * W2[hl];
    #pragma unroll
    for (int off = 16; off; off >>= 1) hr += __shfl_xor(hr, off);
    float g = 1.f / (1.f + __expf(-(hr + b2[0])));
    gctx[(size_t)row * 64 + lane] = f2bf(cv * g);
  }
}

// ---------------- big GEMM body: 128x64 tile, BK=64, 2-phase pipeline ---------
// MODE 0: bf16 out * scale. MODE 2: fp32 out + bias.
template<int MODE>
DEV void gemm128_body(const u16* __restrict__ A, const u16* __restrict__ BT,
                      void* __restrict__ Cp, const float* __restrict__ bias,
                      int m0, int n0, float scale,
                      u16* As, u16* Bs) {
  const int K = 512, N = 512;
  const int lane = threadIdx.x & 63, wave = threadIdx.x >> 6;
  const int quad = lane >> 4, l16 = lane & 15;
  const int wr = wave >> 1, wc = wave & 1;

  const int sr  = lane >> 3;                 // subrow 0..7 within 8-row group
  const int sc8 = ((lane & 7) ^ sr) * 8;     // pre-swizzled source col (u16)
  const u16* gA = A + (size_t)(m0 + wave * 32 + sr) * K + sc8;
  const u16* gB = BT + (size_t)(n0 + wave * 16 + sr) * K + sc8;

  auto STAGE = [&](int k0, int buf) {
    u16* dA = As + buf * 8192 + wave * 2048;     // 32 rows x 64
    #pragma unroll
    for (int j = 0; j < 4; ++j)
      gld16(gA + k0 + (size_t)(j * 8) * K, dA + j * 512);
    u16* dB = Bs + buf * 4096 + wave * 1024;     // 16 rows x 64
    #pragma unroll
    for (int j = 0; j < 2; ++j)
      gld16(gB + k0 + (size_t)(j * 8) * K, dB + j * 512);
  };

  facc acc[4][2] = {};
  STAGE(0, 0);
  int buf = 0;
  for (int k0 = 0; k0 < K; k0 += 64) {
    asm volatile("s_waitcnt vmcnt(0)" ::: "memory");
    __builtin_amdgcn_s_barrier();
    if (k0 + 64 < K) STAGE(k0 + 64, buf ^ 1);    // in flight under compute
    const u16* Ah = As + buf * 8192;
    const u16* Bh = Bs + buf * 4096;
    #pragma unroll
    for (int hh = 0; hh < 2; ++hh) {
      frag16 af[4], bfr[2];
      #pragma unroll
      for (int rt = 0; rt < 4; ++rt) {
        int row = wr * 64 + rt * 16 + l16;
        int ch = (hh * 4 + quad) ^ (row & 7);
        af[rt] = *(const frag16*)(Ah + row * 64 + ch * 8);
      }
      #pragma unroll
      for (int ct = 0; ct < 2; ++ct) {
        int row = wc * 32 + ct * 16 + l16;
        int ch = (hh * 4 + quad) ^ (row & 7);
        bfr[ct] = *(const frag16*)(Bh + row * 64 + ch * 8);
      }
      #pragma unroll
      for (int rt = 0; rt < 4; ++rt)
        #pragma unroll
        for (int ct = 0; ct < 2; ++ct)
          acc[rt][ct] = __builtin_amdgcn_mfma_f32_16x16x32_bf16(af[rt], bfr[ct], acc[rt][ct], 0, 0, 0);
    }
    buf ^= 1;
  }

  #pragma unroll
  for (int rt = 0; rt < 4; ++rt) {
    #pragma unroll
    for (int ct = 0; ct < 2; ++ct) {
      int col = n0 + wc * 32 + ct * 16 + l16;
      int r0g = m0 + wr * 64 + rt * 16 + quad * 4;
      if (MODE == 0) {
        u16* C = (u16*)Cp;
        #pragma unroll
        for (int r = 0; r < 4; ++r)
          C[(size_t)(r0g + r) * N + col] = f2bf(acc[rt][ct][r] * scale);
      } else {
        float* C = (float*)Cp;
        float bv = bias[col];
        #pragma unroll
        for (int r = 0; r < 4; ++r)
          C[(size_t)(r0g + r) * N + col] = acc[rt][ct][r] + bv;
      }
    }
  }
}

// ---------------- K2: q-projection (blocks 0..511) + fused k/v (512..1535) ----
__global__ __launch_bounds__(256) void proj_kernel(const u16* __restrict__ xb,
    const u16* __restrict__ WqT, u16* __restrict__ qb,
    const u16* __restrict__ gctx, const u16* __restrict__ BkT,
    const u16* __restrict__ BvT, u16* __restrict__ Kp, u16* __restrict__ Vp) {
  __shared__ __align__(16) u16 As[2 * 128 * 64];
  __shared__ __align__(16) u16 Bs[2 * 64 * 64];
  int bid = blockIdx.x;
  if (bid < 512) {
    int n0 = (bid & 7) * 64, m0 = (bid >> 3) * 128;
    gemm128_body<0>(xb, WqT, qb, nullptr, m0, n0,
                    0.125f * 1.4426950408889634f, As, Bs);
    return;
  }
  // fused k+v projection, K=64, fragment-packed epilogues
  bid -= 512;
  const int Kd = 64;
  int lane = threadIdx.x & 63, wave = threadIdx.x >> 6;
  int quad = lane >> 4, l16 = lane & 15;
  int wr = wave >> 1, wc = wave & 1;
  int rowBase = (bid >> 3) * 64 + wr * 32;
  int colBase = (bid & 7) * 64 + wc * 32;
  facc ak[2][2] = {}, av[2][2] = {};
  const u16* a0 = gctx + (size_t)(rowBase + l16) * Kd + quad * 8;
  const u16* a1 = a0 + (size_t)16 * Kd;
  const u16* bk0 = BkT + (size_t)(colBase + l16) * Kd + quad * 8;
  const u16* bk1 = bk0 + (size_t)16 * Kd;
  const u16* bv0 = BvT + (size_t)(colBase + l16) * Kd + quad * 8;
  const u16* bv1 = bv0 + (size_t)16 * Kd;
  #pragma unroll
  for (int kk = 0; kk < Kd; kk += 32) {
    frag16 af0 = *(const frag16*)(a0 + kk);
    frag16 af1 = *(const frag16*)(a1 + kk);
    frag16 k0 = *(const frag16*)(bk0 + kk);
    frag16 k1 = *(const frag16*)(bk1 + kk);
    frag16 v0 = *(const frag16*)(bv0 + kk);
    frag16 v1 = *(const frag16*)(bv1 + kk);
    ak[0][0] = __builtin_amdgcn_mfma_f32_16x16x32_bf16(af0, k0, ak[0][0], 0, 0, 0);
    ak[0][1] = __builtin_amdgcn_mfma_f32_16x16x32_bf16(af0, k1, ak[0][1], 0, 0, 0);
    ak[1][0] = __builtin_amdgcn_mfma_f32_16x16x32_bf16(af1, k0, ak[1][0], 0, 0, 0);
    ak[1][1] = __builtin_amdgcn_mfma_f32_16x16x32_bf16(af1, k1, ak[1][1], 0, 0, 0);
    av[0][0] = __builtin_amdgcn_mfma_f32_16x16x32_bf16(af0, v0, av[0][0], 0, 0, 0);
    av[0][1] = __builtin_amdgcn_mfma_f32_16x16x32_bf16(af0, v1, av[0][1], 0, 0, 0);
    av[1][0] = __builtin_amdgcn_mfma_f32_16x16x32_bf16(af1, v0, av[1][0], 0, 0, 0);
    av[1][1] = __builtin_amdgcn_mfma_f32_16x16x32_bf16(af1, v1, av[1][1], 0, 0, 0);
  }
  #pragma unroll
  for (int rt = 0; rt < 2; ++rt) {
    #pragma unroll
    for (int ct = 0; ct < 2; ++ct) {
      int col = colBase + ct * 16 + l16;
      int r0g = rowBase + rt * 16 + quad * 4;
      int hh = col >> 6, d = col & 63;
      int b = r0g >> 11;
      #pragma unroll
      for (int r = 0; r < 4; ++r) {
        int m = (r0g + r) & 2047;
        size_t addr = ((((size_t)(b * 8 + hh) * 64 + (m >> 5)) * 4 + (d >> 4)) * 64
                       + ((d >> 3) & 1) * 32 + (m & 31)) * 8 + (d & 7);
        Kp[addr] = f2bf(ak[rt][ct][r]);
      }
      int m = r0g & 2047;
      size_t addr = ((((size_t)(b * 8 + hh) * 64 + (m >> 5)) * 4
                      + ((m >> 4) & 1) * 2 + (d >> 5)) * 64
                     + ((m >> 3) & 1) * 32 + (d & 31)) * 8 + (m & 7);
      ushort4 o;
      o.x = f2bf(av[rt][ct][0]); o.y = f2bf(av[rt][ct][1]);
      o.z = f2bf(av[rt][ct][2]); o.w = f2bf(av[rt][ct][3]);
      *(ushort4*)(Vp + addr) = o;
    }
  }
}

// ---------------- flash attention: 2-way key-split, 64-key groups kept --------
// qb pre-scaled by 0.125*log2(e). Kp/Vp fragment-packed.
// R1-R4: intra-wave scheduling null. R5: key-split with HALVED groups = -10%
// (per-key overhead doubled -- confounded). This round: clean TLP test --
// wave (wq,ws) keeps the EXACT per-group structure of the 50.4us kernel
// (64-key groups, 2-tile ILP, Lacc via MFMA) but covers 1024 keys (16 groups).
// Single-buffered LDS [ws][tile] = 32KB -> grid 1024 = 4 blocks/CU =
// 4 waves/SIMD, each from a DIFFERENT block (independent barrier cadences:
// one block's stage-drain hides under another's MFMA burst).
// Cross-split merge is pure adds via LDS (no running max in this softmax).
__global__ __launch_bounds__(256, 4) void attn_kernel(
    const u16* __restrict__ qb, const u16* __restrict__ Kp,
    const u16* __restrict__ Vp, u16* __restrict__ ob) {
  const int lane = threadIdx.x & 63, wave = threadIdx.x >> 6;
  const int wq = wave & 1;            // q-tile within block
  const int ws = wave >> 1;           // key-split half
  const int l32 = lane & 31;
  const int hi = lane >> 5;           // half-wave index
  const int bid = blockIdx.x;
  const int bh = bid & 31;            // low bits -> XCD locality
  const int qpair = bid >> 5;         // 0..31
  const int b = bh >> 3, h = bh & 7;
  const int q0 = qpair * 64 + wq * 32;
  const int rowg = b * 2048 + q0 + l32;

  __shared__ __align__(16) u16 sK[2][2][2048], sV[2][2][2048];  // [ws][tile][..]

  const u16* qp = qb + (size_t)rowg * 512 + h * 64 + hi * 8;
  frag16 qf0 = *(const frag16*)(qp);
  frag16 qf1 = *(const frag16*)(qp + 16);
  frag16 qf2 = *(const frag16*)(qp + 32);
  frag16 qf3 = *(const frag16*)(qp + 48);

  frag16 ones;
  #pragma unroll
  for (int i = 0; i < 8; ++i) ones[i] = (short)0x3F80;   // bf16 1.0

  facc16 O0 = {}, O1 = {}, Lacc = {};

  const size_t ts = 2048;  // u16 per 32-key tile
  // this wave's keys: tiles [bh*64 + ws*32 + 2g, +2g+1], wq-half of each tile
  const u16* kpb = Kp + (size_t)(bh * 64 + ws * 32) * ts + wq * 1024 + lane * 8;
  const u16* vpb = Vp + (size_t)(bh * 64 + ws * 32) * ts + wq * 1024 + lane * 8;

  // stage group g (2 tiles of 32 keys) into this ws's buffers; 8 gld16/wave
  auto STAGE = [&](int g) {
    const size_t t2 = (size_t)(2 * g) * ts;
    gld16(kpb + t2,            &sK[ws][0][0] + wq * 1024);
    gld16(kpb + t2 + 512,      &sK[ws][0][0] + wq * 1024 + 512);
    gld16(kpb + t2 + ts,       &sK[ws][1][0] + wq * 1024);
    gld16(kpb + t2 + ts + 512, &sK[ws][1][0] + wq * 1024 + 512);
    gld16(vpb + t2,            &sV[ws][0][0] + wq * 1024);
    gld16(vpb + t2 + 512,      &sV[ws][0][0] + wq * 1024 + 512);
    gld16(vpb + t2 + ts,       &sV[ws][1][0] + wq * 1024);
    gld16(vpb + t2 + ts + 512, &sV[ws][1][0] + wq * 1024 + 512);
  };

  #pragma unroll 1
  for (int g = 0; g < 16; ++g) {
    __syncthreads();                  // all waves done reading group g-1
    STAGE(g);
    __syncthreads();                  // vmcnt(0) drain: group g landed

    frag16 kfa[4], kfb[4];
    #pragma unroll
    for (int i = 0; i < 4; ++i) {
      kfa[i] = *(const frag16*)(&sK[ws][0][0] + i * 512 + lane * 8);
      kfb[i] = *(const frag16*)(&sK[ws][1][0] + i * 512 + lane * 8);
    }

    // two independent S chains (ILP x2)
    facc16 Sa = {}, Sb = {};
    Sa = __builtin_amdgcn_mfma_f32_32x32x16_bf16(kfa[0], qf0, Sa, 0, 0, 0);
    Sb = __builtin_amdgcn_mfma_f32_32x32x16_bf16(kfb[0], qf0, Sb, 0, 0, 0);
    Sa = __builtin_amdgcn_mfma_f32_32x32x16_bf16(kfa[1], qf1, Sa, 0, 0, 0);
    Sb = __builtin_amdgcn_mfma_f32_32x32x16_bf16(kfb[1], qf1, Sb, 0, 0, 0);
    Sa = __builtin_amdgcn_mfma_f32_32x32x16_bf16(kfa[2], qf2, Sa, 0, 0, 0);
    Sb = __builtin_amdgcn_mfma_f32_32x32x16_bf16(kfb[2], qf2, Sb, 0, 0, 0);
    Sa = __builtin_amdgcn_mfma_f32_32x32x16_bf16(kfa[3], qf3, Sa, 0, 0, 0);
    Sb = __builtin_amdgcn_mfma_f32_32x32x16_bf16(kfb[3], qf3, Sb, 0, 0, 0);

    float ea[16], eb[16];
    #pragma unroll
    for (int r = 0; r < 16; ++r) { ea[r] = __builtin_amdgcn_exp2f(Sa[r]);
                                   eb[r] = __builtin_amdgcn_exp2f(Sb[r]); }

    // S^T C-layout -> P B-operand: truncating pack, half-wave dword swap.
    unsigned pua[2][4], pub[2][4];
    #pragma unroll
    for (int c = 0; c < 2; ++c) {
      {
        const float* ee = ea + c * 8;
        unsigned L0 = pkbf_t(ee[0], ee[1]);
        unsigned L1 = pkbf_t(ee[2], ee[3]);
        unsigned H0 = pkbf_t(ee[4], ee[5]);
        unsigned H1 = pkbf_t(ee[6], ee[7]);
        unsigned Y0 = hi ? L0 : H0;
        unsigned Y1 = hi ? L1 : H1;
        unsigned X0 = (unsigned)__shfl_xor((int)Y0, 32);
        unsigned X1 = (unsigned)__shfl_xor((int)Y1, 32);
        pua[c][0] = hi ? X0 : L0;
        pua[c][1] = hi ? X1 : L1;
        pua[c][2] = hi ? H0 : X0;
        pua[c][3] = hi ? H1 : X1;
      }
      {
        const float* ee = eb + c * 8;
        unsigned L0 = pkbf_t(ee[0], ee[1]);
        unsigned L1 = pkbf_t(ee[2], ee[3]);
        unsigned H0 = pkbf_t(ee[4], ee[5]);
        unsigned H1 = pkbf_t(ee[6], ee[7]);
        unsigned Y0 = hi ? L0 : H0;
        unsigned Y1 = hi ? L1 : H1;
        unsigned X0 = (unsigned)__shfl_xor((int)Y0, 32);
        unsigned X1 = (unsigned)__shfl_xor((int)Y1, 32);
        pub[c][0] = hi ? X0 : L0;
        pub[c][1] = hi ? X1 : L1;
        pub[c][2] = hi ? H0 : X0;
        pub[c][3] = hi ? H1 : X1;
      }
    }
    frag16 Pa0 = *(frag16*)&pua[0][0];
    frag16 Pa1 = *(frag16*)&pua[1][0];
    frag16 Pb0 = *(frag16*)&pub[0][0];
    frag16 Pb1 = *(frag16*)&pub[1][0];

    // denominator on the MFMA pipe
    Lacc = __builtin_amdgcn_mfma_f32_32x32x16_bf16(ones, Pa0, Lacc, 0, 0, 0);
    Lacc = __builtin_amdgcn_mfma_f32_32x32x16_bf16(ones, Pa1, Lacc, 0, 0, 0);
    Lacc = __builtin_amdgcn_mfma_f32_32x32x16_bf16(ones, Pb0, Lacc, 0, 0, 0);
    Lacc = __builtin_amdgcn_mfma_f32_32x32x16_bf16(ones, Pb1, Lacc, 0, 0, 0);

    frag16 vfa[4], vfb[4];
    #pragma unroll
    for (int i = 0; i < 4; ++i) {
      vfa[i] = *(const frag16*)(&sV[ws][0][0] + i * 512 + lane * 8);
      vfb[i] = *(const frag16*)(&sV[ws][1][0] + i * 512 + lane * 8);
    }

    O0 = __builtin_amdgcn_mfma_f32_32x32x16_bf16(vfa[0], Pa0, O0, 0, 0, 0);
    O1 = __builtin_amdgcn_mfma_f32_32x32x16_bf16(vfa[1], Pa0, O1, 0, 0, 0);
    O0 = __builtin_amdgcn_mfma_f32_32x32x16_bf16(vfa[2], Pa1, O0, 0, 0, 0);
    O1 = __builtin_amdgcn_mfma_f32_32x32x16_bf16(vfa[3], Pa1, O1, 0, 0, 0);
    O0 = __builtin_amdgcn_mfma_f32_32x32x16_bf16(vfb[0], Pb0, O0, 0, 0, 0);
    O1 = __builtin_amdgcn_mfma_f32_32x32x16_bf16(vfb[1], Pb0, O1, 0, 0, 0);
    O0 = __builtin_amdgcn_mfma_f32_32x32x16_bf16(vfb[2], Pb1, O0, 0, 0, 0);
    O1 = __builtin_amdgcn_mfma_f32_32x32x16_bf16(vfb[3], Pb1, O1, 0, 0, 0);
  }

  // ---- merge the two key-split halves via LDS (pure adds, no rescale) ----
  float* mO = (float*)&sK[0][0][0];   // 32 x 128 floats = 16KB (all of sK)
  float* mL = (float*)&sV[0][0][0];   // 128 floats
  __syncthreads();                    // all compute + LDS reads done
  if (ws == 1) {
    #pragma unroll
    for (int r = 0; r < 16; ++r) {
      mO[r * 128 + wq * 64 + lane]        = O0[r];
      mO[(r + 16) * 128 + wq * 64 + lane] = O1[r];
    }
    mL[wq * 64 + lane] = Lacc[0];
  }
  __syncthreads();
  if (ws == 0) {
    #pragma unroll
    for (int r = 0; r < 16; ++r) {
      O0[r] += mO[r * 128 + wq * 64 + lane];
      O1[r] += mO[(r + 16) * 128 + wq * 64 + lane];
    }
    float rinv = 1.0f / (Lacc[0] + mL[wq * 64 + lane]);

    // O^T C-layout: col=q=l32, row=d = dt*32 + 8*rq + 4*hi + (reg&3).
    u16* op = ob + (size_t)rowg * 512 + h * 64;
    #pragma unroll
    for (int dt = 0; dt < 2; ++dt) {
      #pragma unroll
      for (int rq = 0; rq < 4; ++rq) {
        float v0e, v1e, v2e, v3e;
        if (dt == 0) { v0e = O0[rq*4]; v1e = O0[rq*4+1]; v2e = O0[rq*4+2]; v3e = O0[rq*4+3]; }
        else         { v0e = O1[rq*4]; v1e = O1[rq*4+1]; v2e = O1[rq*4+2]; v3e = O1[rq*4+3]; }
        uint2 pk;
        pk.x = pkbf(v0e * rinv, v1e * rinv);
        pk.y = pkbf(v2e * rinv, v3e * rinv);
        int d0 = dt * 32 + 8 * rq + 4 * hi;
        *(uint2*)(op + d0) = pk;
      }
    }
  }
}

// ---------------- out-projection GEMM ----------------------------------------
__global__ __launch_bounds__(256) void gemm_out(const u16* __restrict__ A,
    const u16* __restrict__ BT, float* __restrict__ C,
    const float* __restrict__ bias) {
  __shared__ __align__(16) u16 As[2 * 128 * 64];
  __shared__ __align__(16) u16 Bs[2 * 64 * 64];
  int n0 = (blockIdx.x & 7) * 64, m0 = (blockIdx.x >> 3) * 128;
  gemm128_body<2>(A, BT, C, bias, m0, n0, 1.f, As, Bs);
}

// ---------------- launch ------------------------------------------------------
extern "C" void kernel_launch(void* const* d_in, const int* in_sizes, int n_in,
                              void* d_out, int out_size, void* d_ws, size_t ws_size,
                              hipStream_t stream) {
  const float* x   = (const float*)d_in[0];
  const float* ctx = (const float*)d_in[1];
  const float* Wq  = (const float*)d_in[2];
  const float* Wk  = (const float*)d_in[3];
  const float* Wv  = (const float*)d_in[4];
  const float* W1  = (const float*)d_in[5];
  const float* b1  = (const float*)d_in[6];
  const float* W2  = (const float*)d_in[7];
  const float* b2  = (const float*)d_in[8];
  const float* Wo  = (const float*)d_in[9];
  const float* bo  = (const float*)d_in[10];
  float* out = (float*)d_out;

  char* ws = (char*)d_ws;
  size_t off = 0;
  auto alloc = [&](size_t bytes) {
    char* p = ws + off;
    off += (bytes + 255) & ~(size_t)255;
    return p;
  };
  u16* xb    = (u16*)alloc(8192ull * 512 * 2);
  u16* qb    = (u16*)alloc(8192ull * 512 * 2);
  u16* Kp    = (u16*)alloc(8192ull * 512 * 2);
  u16* Vp    = (u16*)alloc(8192ull * 512 * 2);
  u16* ob    = (u16*)alloc(8192ull * 512 * 2);
  u16* gctx  = (u16*)alloc(8192ull * 64 * 2);
  u16* WqT   = (u16*)alloc(512ull * 512 * 2);
  u16* WkT   = (u16*)alloc(512ull * 64 * 2);
  u16* WvT   = (u16*)alloc(512ull * 64 * 2);
  u16* WoT   = (u16*)alloc(512ull * 512 * 2);

  prep_gate_kernel<<<3216, 256, 0, stream>>>((const float4*)x, Wq, Wk, Wv, Wo,
                                             ctx, W1, b1, W2, b2,
                                             xb, WqT, WkT, WvT, WoT, gctx);
  proj_kernel<<<1536, 256, 0, stream>>>(xb, WqT, qb, gctx, WkT, WvT, Kp, Vp);
  attn_kernel<<<1024, 256, 0, stream>>>(qb, Kp, Vp, ob);
  gemm_out<<<512, 256, 0, stream>>>(ob, WoT, out, bo);
}

// Round 8
// 166.669 us; speedup vs baseline: 1.0127x; 1.0127x over previous
//
#include <hip/hip_runtime.h>

typedef unsigned short u16;
typedef unsigned int u32;
using frag16 = __attribute__((ext_vector_type(8))) short;   // 8 x bf16 (4 VGPRs)
using facc   = __attribute__((ext_vector_type(4))) float;   // 4 x fp32 acc
using facc16 = __attribute__((ext_vector_type(16))) float;  // 16 x fp32 acc

#define DEV static __device__ __forceinline__

DEV u16 f2bf(float f) {
  union { float f; unsigned u; } v; v.f = f;
  unsigned r = v.u + 0x7fffu + ((v.u >> 16) & 1u);
  return (u16)(r >> 16);
}
DEV unsigned fbits(float f) {
  union { float f; unsigned u; } v; v.f = f;
  return v.u;
}
// pack two fp32 -> two bf16 (lo in low half), round-half-up
DEV unsigned pkbf(float lo, float hi) {
  return __builtin_amdgcn_perm(fbits(hi) + 0x8000u, fbits(lo) + 0x8000u, 0x07060302u);
}
// truncating pack (no rounding adds) -- bias cancels num/denom for P.
DEV unsigned pkbf_t(float lo, float hi) {
  return __builtin_amdgcn_perm(fbits(hi), fbits(lo), 0x07060302u);
}
// async global->LDS, 16B per lane. LDS dest = wave-uniform base + lane*16.
DEV void gld16(const u16* g, u16* l) {
  __builtin_amdgcn_global_load_lds(
      (__attribute__((address_space(1))) unsigned int*)(g),
      (__attribute__((address_space(3))) unsigned int*)(l), 16, 0, 0);
}

// ---------------- K1: x cvt (0..1023, 64B/thread) + wtrans + gate -------------
__global__ __launch_bounds__(256) void prep_gate_kernel(const float4* __restrict__ x,
    const float* __restrict__ Wq, const float* __restrict__ Wk,
    const float* __restrict__ Wv, const float* __restrict__ Wo,
    const float* __restrict__ ctx, const float* __restrict__ W1,
    const float* __restrict__ b1, const float* __restrict__ W2,
    const float* __restrict__ b2,
    u16* __restrict__ xb, u16* __restrict__ WqT, u16* __restrict__ WkT,
    u16* __restrict__ WvT, u16* __restrict__ WoT, u16* __restrict__ gctx) {
  int bid = blockIdx.x;
  if (bid < 1024) {
    // x -> bf16: 4 float4 (64B) per thread
    int id = bid * 256 + threadIdx.x;
    const float4* xp = x + (size_t)id * 4;
    u16* op = xb + (size_t)id * 16;
    #pragma unroll
    for (int j = 0; j < 4; ++j) {
      float4 v = xp[j];
      ushort4 o;
      o.x = f2bf(v.x); o.y = f2bf(v.y); o.z = f2bf(v.z); o.w = f2bf(v.w);
      *(ushort4*)(op + j * 4) = o;
    }
  } else if (bid < 1168) {
    // 64x64 tile transpose via LDS: coalesced read AND write
    int job = bid - 1024;  // 0..143
    const float* W; u16* WT; int K, tile;
    if (job < 64)      { W = Wq; WT = WqT; K = 512; tile = job; }
    else if (job < 72) { W = Wk; WT = WkT; K = 64;  tile = job - 64; }
    else if (job < 80) { W = Wv; WT = WvT; K = 64;  tile = job - 72; }
    else               { W = Wo; WT = WoT; K = 512; tile = job - 80; }
    int tilesK = K >> 6;
    int tr = tile % tilesK, tc = tile / tilesK;
    __shared__ float tl[64][65];
    int c = threadIdx.x & 63, r4 = threadIdx.x >> 6;
    #pragma unroll
    for (int it = 0; it < 16; ++it) {
      int kk = it * 4 + r4;
      tl[kk][c] = W[(size_t)(tr * 64 + kk) * 512 + tc * 64 + c];
    }
    __syncthreads();
    #pragma unroll
    for (int it = 0; it < 16; ++it) {
      int nn = it * 4 + r4;
      WT[(size_t)(tc * 64 + nn) * K + tr * 64 + c] = f2bf(tl[c][nn]);
    }
  } else {
    // gate: gctx = bf16(ctx * sigmoid(relu(ctx@W1+b1)@W2+b2))
    int wave = threadIdx.x >> 6, lane = threadIdx.x & 63;
    int hi = lane >> 5, hl = lane & 31;
    int row = (bid - 1168) * 4 + wave;          // 8192 rows
    __shared__ float sc[4][64];
    float cv = ctx[(size_t)row * 64 + lane];
    sc[wave][lane] = cv;
    __syncthreads();
    float hp = 0.f;
    #pragma unroll
    for (int i = 0; i < 32; ++i) {
      int ii = hi * 32 + i;
      hp += sc[wave][ii] * W1[ii * 32 + hl];
    }
    hp += __shfl_xor(hp, 32);                    // full dot for unit hl
    float hr = fmaxf(hp + b1[hl], 0.f) * W2[hl];
    #pragma unroll
    for (int off = 16; off; off >>= 1) hr += __shfl_xor(hr, off);
    float g = 1.f / (1.f + __expf(-(hr + b2[0])));
    gctx[(size_t)row * 64 + lane] = f2bf(cv * g);
  }
}

// ---------------- big GEMM body: 128x64 tile, BK=64, 2-phase pipeline ---------
// Double-buffered LDS with XOR-swizzled 16B chunks (pre-swizzled global
// source; gld16 dest stays linear). Per K-step: wait(k) -> barrier ->
// STAGE(k+1) -> compute(k): stage latency hides under MFMAs.
// MODE 0: bf16 out * scale. MODE 2: fp32 out + bias.
template<int MODE>
DEV void gemm128_body(const u16* __restrict__ A, const u16* __restrict__ BT,
                      void* __restrict__ Cp, const float* __restrict__ bias,
                      int m0, int n0, float scale,
                      u16* As, u16* Bs) {
  const int K = 512, N = 512;
  const int lane = threadIdx.x & 63, wave = threadIdx.x >> 6;
  const int quad = lane >> 4, l16 = lane & 15;
  const int wr = wave >> 1, wc = wave & 1;

  const int sr  = lane >> 3;                 // subrow 0..7 within 8-row group
  const int sc8 = ((lane & 7) ^ sr) * 8;     // pre-swizzled source col (u16)
  const u16* gA = A + (size_t)(m0 + wave * 32 + sr) * K + sc8;
  const u16* gB = BT + (size_t)(n0 + wave * 16 + sr) * K + sc8;

  auto STAGE = [&](int k0, int buf) {
    u16* dA = As + buf * 8192 + wave * 2048;     // 32 rows x 64
    #pragma unroll
    for (int j = 0; j < 4; ++j)
      gld16(gA + k0 + (size_t)(j * 8) * K, dA + j * 512);
    u16* dB = Bs + buf * 4096 + wave * 1024;     // 16 rows x 64
    #pragma unroll
    for (int j = 0; j < 2; ++j)
      gld16(gB + k0 + (size_t)(j * 8) * K, dB + j * 512);
  };

  facc acc[4][2] = {};
  STAGE(0, 0);
  int buf = 0;
  for (int k0 = 0; k0 < K; k0 += 64) {
    asm volatile("s_waitcnt vmcnt(0)" ::: "memory");
    __builtin_amdgcn_s_barrier();
    if (k0 + 64 < K) STAGE(k0 + 64, buf ^ 1);    // in flight under compute
    const u16* Ah = As + buf * 8192;
    const u16* Bh = Bs + buf * 4096;
    #pragma unroll
    for (int hh = 0; hh < 2; ++hh) {
      frag16 af[4], bfr[2];
      #pragma unroll
      for (int rt = 0; rt < 4; ++rt) {
        int row = wr * 64 + rt * 16 + l16;
        int ch = (hh * 4 + quad) ^ (row & 7);
        af[rt] = *(const frag16*)(Ah + row * 64 + ch * 8);
      }
      #pragma unroll
      for (int ct = 0; ct < 2; ++ct) {
        int row = wc * 32 + ct * 16 + l16;
        int ch = (hh * 4 + quad) ^ (row & 7);
        bfr[ct] = *(const frag16*)(Bh + row * 64 + ch * 8);
      }
      #pragma unroll
      for (int rt = 0; rt < 4; ++rt)
        #pragma unroll
        for (int ct = 0; ct < 2; ++ct)
          acc[rt][ct] = __builtin_amdgcn_mfma_f32_16x16x32_bf16(af[rt], bfr[ct], acc[rt][ct], 0, 0, 0);
    }
    buf ^= 1;
  }

  #pragma unroll
  for (int rt = 0; rt < 4; ++rt) {
    #pragma unroll
    for (int ct = 0; ct < 2; ++ct) {
      int col = n0 + wc * 32 + ct * 16 + l16;
      int r0g = m0 + wr * 64 + rt * 16 + quad * 4;
      if (MODE == 0) {
        u16* C = (u16*)Cp;
        #pragma unroll
        for (int r = 0; r < 4; ++r)
          C[(size_t)(r0g + r) * N + col] = f2bf(acc[rt][ct][r] * scale);
      } else {
        float* C = (float*)Cp;
        float bv = bias[col];
        #pragma unroll
        for (int r = 0; r < 4; ++r)
          C[(size_t)(r0g + r) * N + col] = acc[rt][ct][r] + bv;
      }
    }
  }
}

// ---------------- K2: q-projection (blocks 0..511) + fused k/v (512..1535) ----
__global__ __launch_bounds__(256) void proj_kernel(const u16* __restrict__ xb,
    const u16* __restrict__ WqT, u16* __restrict__ qb,
    const u16* __restrict__ gctx, const u16* __restrict__ BkT,
    const u16* __restrict__ BvT, u16* __restrict__ Kp, u16* __restrict__ Vp) {
  __shared__ __align__(16) u16 As[2 * 128 * 64];
  __shared__ __align__(16) u16 Bs[2 * 64 * 64];
  int bid = blockIdx.x;
  if (bid < 512) {
    int n0 = (bid & 7) * 64, m0 = (bid >> 3) * 128;
    gemm128_body<0>(xb, WqT, qb, nullptr, m0, n0,
                    0.125f * 1.4426950408889634f, As, Bs);
    return;
  }
  // fused k+v projection, K=64, fragment-packed epilogues
  bid -= 512;
  const int Kd = 64;
  int lane = threadIdx.x & 63, wave = threadIdx.x >> 6;
  int quad = lane >> 4, l16 = lane & 15;
  int wr = wave >> 1, wc = wave & 1;
  int rowBase = (bid >> 3) * 64 + wr * 32;
  int colBase = (bid & 7) * 64 + wc * 32;
  facc ak[2][2] = {}, av[2][2] = {};
  const u16* a0 = gctx + (size_t)(rowBase + l16) * Kd + quad * 8;
  const u16* a1 = a0 + (size_t)16 * Kd;
  const u16* bk0 = BkT + (size_t)(colBase + l16) * Kd + quad * 8;
  const u16* bk1 = bk0 + (size_t)16 * Kd;
  const u16* bv0 = BvT + (size_t)(colBase + l16) * Kd + quad * 8;
  const u16* bv1 = bv0 + (size_t)16 * Kd;
  #pragma unroll
  for (int kk = 0; kk < Kd; kk += 32) {
    frag16 af0 = *(const frag16*)(a0 + kk);
    frag16 af1 = *(const frag16*)(a1 + kk);
    frag16 k0 = *(const frag16*)(bk0 + kk);
    frag16 k1 = *(const frag16*)(bk1 + kk);
    frag16 v0 = *(const frag16*)(bv0 + kk);
    frag16 v1 = *(const frag16*)(bv1 + kk);
    ak[0][0] = __builtin_amdgcn_mfma_f32_16x16x32_bf16(af0, k0, ak[0][0], 0, 0, 0);
    ak[0][1] = __builtin_amdgcn_mfma_f32_16x16x32_bf16(af0, k1, ak[0][1], 0, 0, 0);
    ak[1][0] = __builtin_amdgcn_mfma_f32_16x16x32_bf16(af1, k0, ak[1][0], 0, 0, 0);
    ak[1][1] = __builtin_amdgcn_mfma_f32_16x16x32_bf16(af1, k1, ak[1][1], 0, 0, 0);
    av[0][0] = __builtin_amdgcn_mfma_f32_16x16x32_bf16(af0, v0, av[0][0], 0, 0, 0);
    av[0][1] = __builtin_amdgcn_mfma_f32_16x16x32_bf16(af0, v1, av[0][1], 0, 0, 0);
    av[1][0] = __builtin_amdgcn_mfma_f32_16x16x32_bf16(af1, v0, av[1][0], 0, 0, 0);
    av[1][1] = __builtin_amdgcn_mfma_f32_16x16x32_bf16(af1, v1, av[1][1], 0, 0, 0);
  }
  #pragma unroll
  for (int rt = 0; rt < 2; ++rt) {
    #pragma unroll
    for (int ct = 0; ct < 2; ++ct) {
      int col = colBase + ct * 16 + l16;
      int r0g = rowBase + rt * 16 + quad * 4;
      int hh = col >> 6, d = col & 63;
      int b = r0g >> 11;
      #pragma unroll
      for (int r = 0; r < 4; ++r) {
        int m = (r0g + r) & 2047;
        size_t addr = ((((size_t)(b * 8 + hh) * 64 + (m >> 5)) * 4 + (d >> 4)) * 64
                       + ((d >> 3) & 1) * 32 + (m & 31)) * 8 + (d & 7);
        Kp[addr] = f2bf(ak[rt][ct][r]);
      }
      int m = r0g & 2047;
      size_t addr = ((((size_t)(b * 8 + hh) * 64 + (m >> 5)) * 4
                      + ((m >> 4) & 1) * 2 + (d >> 5)) * 64
                     + ((m >> 3) & 1) * 32 + (d & 31)) * 8 + (m & 7);
      ushort4 o;
      o.x = f2bf(av[rt][ct][0]); o.y = f2bf(av[rt][ct][1]);
      o.z = f2bf(av[rt][ct][2]); o.w = f2bf(av[rt][ct][3]);
      *(ushort4*)(Vp + addr) = o;
    }
  }
}

// ---------------- flash attention: NJS=1, 2-tile ILP, lsum via MFMA -----------
// Best-measured variant (50.4-50.8us, ~850 TF effective). Structural
// constraint, established R1-R7: per 64-key group the serial chain
// S(MFMA, 4-deep) -> exp2(32x ~8cyc trans) -> pack/shfl -> PV(MFMA) is
// ~2600 cyc wall vs 1280 cyc MFMA floor at 2 waves/SIMD; four schedule
// variants (cross-group pipeline, barrier-free region, counted-vmcnt) and
// two occupancy doublings (key-split x2 ways) all leave MfmaUtil at ~33%.
// Past this plateau requires the fully co-designed inline-asm schedule
// (HK-style T2+T3+T4+T5+T10 combo) -- isolated grafts measured null.
__global__ __launch_bounds__(256, 2) void attn_kernel(
    const u16* __restrict__ qb, const u16* __restrict__ Kp,
    const u16* __restrict__ Vp, u16* __restrict__ ob) {
  const int lane = threadIdx.x & 63, wave = threadIdx.x >> 6;
  const int l32 = lane & 31;
  const int hi = lane >> 5;           // half-wave index
  const int bid = blockIdx.x;
  const int bh = bid & 31;            // low bits -> XCD locality
  const int qblk = bid >> 5;          // 0..15
  const int b = bh >> 3, h = bh & 7;
  const int q0 = (qblk * 4 + wave) * 32;
  const int rowg = b * 2048 + q0 + l32;

  __shared__ __align__(16) u16 sK[2][2][2048], sV[2][2][2048];   // [buf][tile][..]

  const u16* qp = qb + (size_t)rowg * 512 + h * 64 + hi * 8;
  frag16 qf0 = *(const frag16*)(qp);
  frag16 qf1 = *(const frag16*)(qp + 16);
  frag16 qf2 = *(const frag16*)(qp + 32);
  frag16 qf3 = *(const frag16*)(qp + 48);

  frag16 ones;
  #pragma unroll
  for (int i = 0; i < 8; ++i) ones[i] = (short)0x3F80;   // bf16 1.0

  facc16 O0 = {}, O1 = {}, Lacc = {};

  const size_t ts = 2048;  // u16 per 32-key tile
  const u16* kpb = Kp + (size_t)(bh * 64) * ts + wave * 512 + lane * 8;
  const u16* vpb = Vp + (size_t)(bh * 64) * ts + wave * 512 + lane * 8;

  // preload group 0 (tiles 0,1) into buffer 0
  gld16(kpb,      sK[0][0] + wave * 512);
  gld16(kpb + ts, sK[0][1] + wave * 512);
  gld16(vpb,      sV[0][0] + wave * 512);
  gld16(vpb + ts, sV[0][1] + wave * 512);

  for (int g = 0; g < 32; ++g) {
    const int p = g & 1;
    __syncthreads();                    // drains buffer-p loads
    if (g + 1 < 32) {                   // prefetch next group
      const size_t t2 = (size_t)(2 * g + 2) * ts;
      gld16(kpb + t2,      sK[p ^ 1][0] + wave * 512);
      gld16(kpb + t2 + ts, sK[p ^ 1][1] + wave * 512);
      gld16(vpb + t2,      sV[p ^ 1][0] + wave * 512);
      gld16(vpb + t2 + ts, sV[p ^ 1][1] + wave * 512);
    }

    frag16 kfa[4], kfb[4];
    #pragma unroll
    for (int i = 0; i < 4; ++i) {
      kfa[i] = *(const frag16*)(sK[p][0] + i * 512 + lane * 8);
      kfb[i] = *(const frag16*)(sK[p][1] + i * 512 + lane * 8);
    }

    // two independent S chains (ILP x2)
    facc16 Sa = {}, Sb = {};
    Sa = __builtin_amdgcn_mfma_f32_32x32x16_bf16(kfa[0], qf0, Sa, 0, 0, 0);
    Sb = __builtin_amdgcn_mfma_f32_32x32x16_bf16(kfb[0], qf0, Sb, 0, 0, 0);
    Sa = __builtin_amdgcn_mfma_f32_32x32x16_bf16(kfa[1], qf1, Sa, 0, 0, 0);
    Sb = __builtin_amdgcn_mfma_f32_32x32x16_bf16(kfb[1], qf1, Sb, 0, 0, 0);
    Sa = __builtin_amdgcn_mfma_f32_32x32x16_bf16(kfa[2], qf2, Sa, 0, 0, 0);
    Sb = __builtin_amdgcn_mfma_f32_32x32x16_bf16(kfb[2], qf2, Sb, 0, 0, 0);
    Sa = __builtin_amdgcn_mfma_f32_32x32x16_bf16(kfa[3], qf3, Sa, 0, 0, 0);
    Sb = __builtin_amdgcn_mfma_f32_32x32x16_bf16(kfb[3], qf3, Sb, 0, 0, 0);

    float ea[16], eb[16];
    #pragma unroll
    for (int r = 0; r < 16; ++r) { ea[r] = __builtin_amdgcn_exp2f(Sa[r]);
                                   eb[r] = __builtin_amdgcn_exp2f(Sb[r]); }

    // S^T C-layout -> P B-operand: truncating pack, half-wave dword swap.
    unsigned pua[2][4], pub[2][4];
    #pragma unroll
    for (int c = 0; c < 2; ++c) {
      {
        const float* ee = ea + c * 8;
        unsigned L0 = pkbf_t(ee[0], ee[1]);
        unsigned L1 = pkbf_t(ee[2], ee[3]);
        unsigned H0 = pkbf_t(ee[4], ee[5]);
        unsigned H1 = pkbf_t(ee[6], ee[7]);
        unsigned Y0 = hi ? L0 : H0;
        unsigned Y1 = hi ? L1 : H1;
        unsigned X0 = (unsigned)__shfl_xor((int)Y0, 32);
        unsigned X1 = (unsigned)__shfl_xor((int)Y1, 32);
        pua[c][0] = hi ? X0 : L0;
        pua[c][1] = hi ? X1 : L1;
        pua[c][2] = hi ? H0 : X0;
        pua[c][3] = hi ? H1 : X1;
      }
      {
        const float* ee = eb + c * 8;
        unsigned L0 = pkbf_t(ee[0], ee[1]);
        unsigned L1 = pkbf_t(ee[2], ee[3]);
        unsigned H0 = pkbf_t(ee[4], ee[5]);
        unsigned H1 = pkbf_t(ee[6], ee[7]);
        unsigned Y0 = hi ? L0 : H0;
        unsigned Y1 = hi ? L1 : H1;
        unsigned X0 = (unsigned)__shfl_xor((int)Y0, 32);
        unsigned X1 = (unsigned)__shfl_xor((int)Y1, 32);
        pub[c][0] = hi ? X0 : L0;
        pub[c][1] = hi ? X1 : L1;
        pub[c][2] = hi ? H0 : X0;
        pub[c][3] = hi ? H1 : X1;
      }
    }
    frag16 Pa0 = *(frag16*)&pua[0][0];
    frag16 Pa1 = *(frag16*)&pua[1][0];
    frag16 Pb0 = *(frag16*)&pub[0][0];
    frag16 Pb1 = *(frag16*)&pub[1][0];

    // denominator on the MFMA pipe
    Lacc = __builtin_amdgcn_mfma_f32_32x32x16_bf16(ones, Pa0, Lacc, 0, 0, 0);
    Lacc = __builtin_amdgcn_mfma_f32_32x32x16_bf16(ones, Pa1, Lacc, 0, 0, 0);
    Lacc = __builtin_amdgcn_mfma_f32_32x32x16_bf16(ones, Pb0, Lacc, 0, 0, 0);
    Lacc = __builtin_amdgcn_mfma_f32_32x32x16_bf16(ones, Pb1, Lacc, 0, 0, 0);

    frag16 vfa[4], vfb[4];
    #pragma unroll
    for (int i = 0; i < 4; ++i) {
      vfa[i] = *(const frag16*)(sV[p][0] + i * 512 + lane * 8);
      vfb[i] = *(const frag16*)(sV[p][1] + i * 512 + lane * 8);
    }

    O0 = __builtin_amdgcn_mfma_f32_32x32x16_bf16(vfa[0], Pa0, O0, 0, 0, 0);
    O1 = __builtin_amdgcn_mfma_f32_32x32x16_bf16(vfa[1], Pa0, O1, 0, 0, 0);
    O0 = __builtin_amdgcn_mfma_f32_32x32x16_bf16(vfa[2], Pa1, O0, 0, 0, 0);
    O1 = __builtin_amdgcn_mfma_f32_32x32x16_bf16(vfa[3], Pa1, O1, 0, 0, 0);
    O0 = __builtin_amdgcn_mfma_f32_32x32x16_bf16(vfb[0], Pb0, O0, 0, 0, 0);
    O1 = __builtin_amdgcn_mfma_f32_32x32x16_bf16(vfb[1], Pb0, O1, 0, 0, 0);
    O0 = __builtin_amdgcn_mfma_f32_32x32x16_bf16(vfb[2], Pb1, O0, 0, 0, 0);
    O1 = __builtin_amdgcn_mfma_f32_32x32x16_bf16(vfb[3], Pb1, O1, 0, 0, 0);
  }

  // every row of Lacc equals the key-sum for query q = l32
  float rinv = 1.0f / Lacc[0];

  // O^T C-layout: col=q=l32, row=d = dt*32 + 8*rq + 4*hi + (reg&3). Final bf16.
  u16* op = ob + (size_t)rowg * 512 + h * 64;
  #pragma unroll
  for (int dt = 0; dt < 2; ++dt) {
    #pragma unroll
    for (int rq = 0; rq < 4; ++rq) {
      float v0, v1, v2, v3;
      if (dt == 0) { v0 = O0[rq*4]; v1 = O0[rq*4+1]; v2 = O0[rq*4+2]; v3 = O0[rq*4+3]; }
      else         { v0 = O1[rq*4]; v1 = O1[rq*4+1]; v2 = O1[rq*4+2]; v3 = O1[rq*4+3]; }
      uint2 pk;
      pk.x = pkbf(v0 * rinv, v1 * rinv);
      pk.y = pkbf(v2 * rinv, v3 * rinv);
      int d0 = dt * 32 + 8 * rq + 4 * hi;
      *(uint2*)(op + d0) = pk;
    }
  }
}

// ---------------- out-projection GEMM ----------------------------------------
__global__ __launch_bounds__(256) void gemm_out(const u16* __restrict__ A,
    const u16* __restrict__ BT, float* __restrict__ C,
    const float* __restrict__ bias) {
  __shared__ __align__(16) u16 As[2 * 128 * 64];
  __shared__ __align__(16) u16 Bs[2 * 64 * 64];
  int n0 = (blockIdx.x & 7) * 64, m0 = (blockIdx.x >> 3) * 128;
  gemm128_body<2>(A, BT, C, bias, m0, n0, 1.f, As, Bs);
}

// ---------------- launch ------------------------------------------------------
extern "C" void kernel_launch(void* const* d_in, const int* in_sizes, int n_in,
                              void* d_out, int out_size, void* d_ws, size_t ws_size,
                              hipStream_t stream) {
  const float* x   = (const float*)d_in[0];
  const float* ctx = (const float*)d_in[1];
  const float* Wq  = (const float*)d_in[2];
  const float* Wk  = (const float*)d_in[3];
  const float* Wv  = (const float*)d_in[4];
  const float* W1  = (const float*)d_in[5];
  const float* b1  = (const float*)d_in[6];
  const float* W2  = (const float*)d_in[7];
  const float* b2  = (const float*)d_in[8];
  const float* Wo  = (const float*)d_in[9];
  const float* bo  = (const float*)d_in[10];
  float* out = (float*)d_out;

  char* ws = (char*)d_ws;
  size_t off = 0;
  auto alloc = [&](size_t bytes) {
    char* p = ws + off;
    off += (bytes + 255) & ~(size_t)255;
    return p;
  };
  u16* xb    = (u16*)alloc(8192ull * 512 * 2);
  u16* qb    = (u16*)alloc(8192ull * 512 * 2);
  u16* Kp    = (u16*)alloc(8192ull * 512 * 2);
  u16* Vp    = (u16*)alloc(8192ull * 512 * 2);
  u16* ob    = (u16*)alloc(8192ull * 512 * 2);
  u16* gctx  = (u16*)alloc(8192ull * 64 * 2);
  u16* WqT   = (u16*)alloc(512ull * 512 * 2);
  u16* WkT   = (u16*)alloc(512ull * 64 * 2);
  u16* WvT   = (u16*)alloc(512ull * 64 * 2);
  u16* WoT   = (u16*)alloc(512ull * 512 * 2);

  prep_gate_kernel<<<3216, 256, 0, stream>>>((const float4*)x, Wq, Wk, Wv, Wo,
                                             ctx, W1, b1, W2, b2,
                                             xb, WqT, WkT, WvT, WoT, gctx);
  proj_kernel<<<1536, 256, 0, stream>>>(xb, WqT, qb, gctx, WkT, WvT, Kp, Vp);
  attn_kernel<<<512, 256, 0, stream>>>(qb, Kp, Vp, ob);
  gemm_out<<<512, 256, 0, stream>>>(ob, WoT, out, bo);
}